// Round 1
// baseline (828.002 us; speedup 1.0000x reference)
//
#include <hip/hip_runtime.h>

#define N_NODES 100000
#define N_EDGES 3200000
#define CH 32
#define NK 9
#define YSTRIDE (NK * CH)  // 288 floats per node

// ---------------------------------------------------------------------------
// Kernel A: y[n,k,o] = sum_i x[n,i] * w[k,i,o]    (1.84 GFLOP, writes 115 MB)
// ---------------------------------------------------------------------------
__global__ __launch_bounds__(256) void yprep_kernel(const float* __restrict__ x,
                                                    const float* __restrict__ w,
                                                    float* __restrict__ y) {
    __shared__ float ws[NK * CH * CH];  // 36 KB
    int tid = threadIdx.x;
    for (int j = tid; j < NK * CH * CH; j += 256) ws[j] = w[j];
    __syncthreads();

    int idx = blockIdx.x * 256 + tid;
    if (idx >= N_NODES * YSTRIDE) return;
    int n = idx / YSTRIDE;
    int r = idx - n * YSTRIDE;
    int k = r >> 5;
    int o = r & 31;
    const float* xr = x + n * CH;
    const float* wk = ws + k * (CH * CH) + o;
    float s = 0.f;
#pragma unroll
    for (int i = 0; i < CH; ++i) s += xr[i] * wk[i * CH];
    y[idx] = s;  // y layout: [n][k][o], coalesced write
}

// ---------------------------------------------------------------------------
// Kernel B (fast): per edge, 32 lanes (one per output channel).
// Only 4 of 9 basis entries are nonzero for degree-1 B-splines.
// ---------------------------------------------------------------------------
__global__ __launch_bounds__(256) void edge_kernel(const float* __restrict__ pseudo,
                                                   const int* __restrict__ ei,
                                                   const float* __restrict__ y,
                                                   float* __restrict__ acc,
                                                   float* __restrict__ deg) {
    int gid = blockIdx.x * 256 + threadIdx.x;
    int e = gid >> 5;
    int o = gid & 31;
    if (e >= N_EDGES) return;

    int row = ei[e];
    int col = ei[N_EDGES + e];

    float pa = fminf(fmaxf(pseudo[2 * e], 0.f), 1.f);
    float pb = fminf(fmaxf(pseudo[2 * e + 1], 0.f), 1.f);
    // hat basis: grid {0, 0.5, 1}; the 2 adjacent grid points get weights
    // (1-2d, 2d) where d = p - 0.5*i0
    int ia = pa < 0.5f ? 0 : 1;
    int ib = pb < 0.5f ? 0 : 1;
    float wa1 = 2.f * (pa - 0.5f * (float)ia);
    float wa0 = 1.f - wa1;
    float wb1 = 2.f * (pb - 0.5f * (float)ib);
    float wb0 = 1.f - wb1;

    const float* yr = y + (size_t)row * YSTRIDE + (ia * 3 + ib) * CH + o;
    // k offsets: (ia,ib)=+0, (ia,ib+1)=+1 -> +CH, (ia+1,ib)=+3 -> +3CH, (ia+1,ib+1)=+4 -> +4CH
    float m = wa0 * wb0 * yr[0]
            + wa0 * wb1 * yr[CH]
            + wa1 * wb0 * yr[3 * CH]
            + wa1 * wb1 * yr[4 * CH];

    atomicAdd(acc + col * CH + o, m);
    if (o == 0) atomicAdd(deg + col, 1.f);
}

// ---------------------------------------------------------------------------
// Kernel B (fallback, no y scratch): combine the 4 weight matrices on the fly
// ---------------------------------------------------------------------------
__global__ __launch_bounds__(256) void edge_direct_kernel(const float* __restrict__ x,
                                                          const float* __restrict__ pseudo,
                                                          const int* __restrict__ ei,
                                                          const float* __restrict__ w,
                                                          float* __restrict__ acc,
                                                          float* __restrict__ deg) {
    __shared__ float ws[NK * CH * CH];
    for (int j = threadIdx.x; j < NK * CH * CH; j += 256) ws[j] = w[j];
    __syncthreads();

    int gid = blockIdx.x * 256 + threadIdx.x;
    int e = gid >> 5;
    int o = gid & 31;
    if (e >= N_EDGES) return;

    int row = ei[e];
    int col = ei[N_EDGES + e];

    float pa = fminf(fmaxf(pseudo[2 * e], 0.f), 1.f);
    float pb = fminf(fmaxf(pseudo[2 * e + 1], 0.f), 1.f);
    int ia = pa < 0.5f ? 0 : 1;
    int ib = pb < 0.5f ? 0 : 1;
    float wa1 = 2.f * (pa - 0.5f * (float)ia);
    float wa0 = 1.f - wa1;
    float wb1 = 2.f * (pb - 0.5f * (float)ib);
    float wb0 = 1.f - wb1;

    const float* w00 = ws + (ia * 3 + ib) * (CH * CH) + o;
    const float* xr = x + row * CH;
    float m = 0.f;
#pragma unroll
    for (int i = 0; i < CH; ++i) {
        float wc = wa0 * wb0 * w00[i * CH]
                 + wa0 * wb1 * w00[CH * CH + i * CH]
                 + wa1 * wb0 * w00[3 * CH * CH + i * CH]
                 + wa1 * wb1 * w00[4 * CH * CH + i * CH];
        m += xr[i] * wc;
    }

    atomicAdd(acc + col * CH + o, m);
    if (o == 0) atomicAdd(deg + col, 1.f);
}

// ---------------------------------------------------------------------------
// Kernel C: out[n,o] = acc[n,o]/max(deg[n],1) + dot(x[n,:], root_w[o,:]) + root_b[o]
// (in-place on d_out)
// ---------------------------------------------------------------------------
__global__ __launch_bounds__(256) void fin_kernel(const float* __restrict__ x,
                                                  const float* __restrict__ rw,
                                                  const float* __restrict__ rb,
                                                  const float* __restrict__ deg,
                                                  float* __restrict__ out) {
    __shared__ float rws[CH * CH];  // stored TRANSPOSED: rws[i*CH + o] = rw[o*CH + i]
    __shared__ float rbs[CH];
    int tid = threadIdx.x;
    for (int j = tid; j < CH * CH; j += 256) {
        int o = j >> 5, i = j & 31;
        rws[i * CH + o] = rw[j];
    }
    if (tid < CH) rbs[tid] = rb[tid];
    __syncthreads();

    int idx = blockIdx.x * 256 + tid;
    if (idx >= N_NODES * CH) return;
    int n = idx >> 5;
    int o = idx & 31;

    float a = out[idx] / fmaxf(deg[n], 1.f);
    const float* xr = x + n * CH;
    float s = rbs[o];
#pragma unroll
    for (int i = 0; i < CH; ++i) s += xr[i] * rws[i * CH + o];  // bank-conflict-free
    out[idx] = a + s;
}

// ---------------------------------------------------------------------------
extern "C" void kernel_launch(void* const* d_in, const int* in_sizes, int n_in,
                              void* d_out, int out_size, void* d_ws, size_t ws_size,
                              hipStream_t stream) {
    const float* x      = (const float*)d_in[0];
    const float* pseudo = (const float*)d_in[1];
    const float* weight = (const float*)d_in[2];
    const float* root_w = (const float*)d_in[3];
    const float* root_b = (const float*)d_in[4];
    const int*   ei     = (const int*)d_in[5];
    float* out = (float*)d_out;

    // ws layout: [0 .. N_NODES*4) degree, [1MB .. 1MB+115.2MB) y (if it fits)
    float* deg = (float*)d_ws;
    size_t yoff = (size_t)1 << 20;
    size_t ybytes = (size_t)N_NODES * YSTRIDE * sizeof(float);
    bool fast = ws_size >= yoff + ybytes;
    float* y = (float*)((char*)d_ws + yoff);

    hipMemsetAsync(d_out, 0, (size_t)N_NODES * CH * sizeof(float), stream);
    hipMemsetAsync(d_ws, 0, (size_t)N_NODES * sizeof(float), stream);

    if (fast) {
        int nblk_y = (N_NODES * YSTRIDE + 255) / 256;  // 112500
        yprep_kernel<<<nblk_y, 256, 0, stream>>>(x, weight, y);
        int nblk_e = (N_EDGES * 32) / 256;  // 400000
        edge_kernel<<<nblk_e, 256, 0, stream>>>(pseudo, ei, y, out, deg);
    } else {
        int nblk_e = (N_EDGES * 32) / 256;
        edge_direct_kernel<<<nblk_e, 256, 0, stream>>>(x, pseudo, ei, weight, out, deg);
    }

    int nblk_f = (N_NODES * CH + 255) / 256;  // 12500
    fin_kernel<<<nblk_f, 256, 0, stream>>>(x, root_w, root_b, deg, out);
}